// Round 10
// baseline (532.069 us; speedup 1.0000x reference)
//
#include <hip/hip_runtime.h>

#define E_DIM 1024
#define NH 16
#define DH 64
#define BSEG 8
#define LQ 512
#define LKV 1024

typedef short bf16x8 __attribute__((ext_vector_type(8)));
typedef float f32x4 __attribute__((ext_vector_type(4)));
typedef unsigned short u16;

// round-to-nearest-even fp32 -> bf16 bits
__device__ __forceinline__ u16 f2bf(float x) {
    unsigned u = __float_as_uint(x);
    u += 0x7FFF + ((u >> 16) & 1);
    return (u16)(u >> 16);
}

// async global->LDS, 16B per lane; lds dest wave-uniform base + lane*16
__device__ __forceinline__ void async16(const void* g, const void* l) {
    __builtin_amdgcn_global_load_lds(
        (const __attribute__((address_space(1))) unsigned int*)g,
        (__attribute__((address_space(3))) unsigned int*)l, 16, 0, 0);
}

// packed RNE f32->bf16 pair -> one u32 (v_cvt_pk_bf16_f32)
__device__ __forceinline__ unsigned pk2(float a, float b) {
    unsigned r;
    asm("v_cvt_pk_bf16_f32 %0, %1, %2" : "=v"(r) : "v"(a), "v"(b));
    return r;
}

// 8 fp32 -> bf16x8 (u16 order: lo0..lo3, hi0..hi3)
__device__ __forceinline__ bf16x8 pk8(f32x4 lo, f32x4 hi) {
    union { unsigned u[4]; bf16x8 v; } r;
    r.u[0] = pk2(lo[0], lo[1]);
    r.u[1] = pk2(lo[2], lo[3]);
    r.u[2] = pk2(hi[0], hi[1]);
    r.u[3] = pk2(hi[2], hi[3]);
    return r.v;
}

// ---------------------------------------------------------------------------
// fp32->bf16 convert for WEIGHTS ONLY (w_in 3072 blocks + w_out 1024 blocks).
// The inputs/queries mirrors are gone: proj stages A as fp32 and converts
// in-register during staging (off the MFMA critical path).
// ---------------------------------------------------------------------------
__global__ __launch_bounds__(256) void cvt_w_kernel(
    const float* __restrict__ w_in, const float* __restrict__ w_out,
    u16* __restrict__ wib, u16* __restrict__ wob)
{
    int blk = blockIdx.x;
    const float* s; u16* d; int base;
    if (blk < 3072) { s = w_in;  d = wib; base = blk; }
    else            { s = w_out; d = wob; base = blk - 3072; }
    int i = base * 256 + threadIdx.x;
    float4 v = ((const float4*)s)[i];
    ushort4 o;
    o.x = f2bf(v.x); o.y = f2bf(v.y); o.z = f2bf(v.z); o.w = f2bf(v.w);
    ((ushort4*)d)[i] = o;
}

// ---------------------------------------------------------------------------
// Fused Q/K/V projection GEMM.  Round-8 skeleton (BK=64 two-half staging,
// launch_bounds(256,5), uniform MFMA order, scatter/sigma' epilogues) with
// ONE change: A (inputs/queries) is read DIRECTLY as fp32 — reg-staged:
//   loadA: 8x global f32x4 (issued at top of compute window, latency hides
//          under MFMA + next barrier), writeA: 16x v_cvt_pk_bf16_f32 +
//          4x ds_write_b128 into the IDENTICAL bf16 LDS layout.
// Fragment reads + MFMA loop untouched (cvt is OFF the critical path —
// the round-2 failure mode).  W keeps the bf16 mirror via async16.
// VGPR budget: 48 base + 32 A-regs + temps ~= 90 < 102 cap (no spill;
// tripwire = WRITE_SIZE balloon, round-7 lesson).
// ---------------------------------------------------------------------------
__global__ __launch_bounds__(256, 5) void proj_gemm_kernel(
    const float* __restrict__ inputs, const float* __restrict__ queries,
    const u16* __restrict__ w_in_b, const float* __restrict__ b_in,
    u16* __restrict__ Kf, u16* __restrict__ Qf, u16* __restrict__ Vf)
{
    __shared__ u16 As[2][128 * 32];
    __shared__ u16 Ws[2][128 * 32];

    const int bid = blockIdx.x;
    const bool isQ = (bid >= 1024);
    const int x = bid & 7;
    int bx, by;
    if (!isQ) { int i = bid >> 3;          bx = i >> 3; by = x * 8 + (i & 7); }
    else      { int i = (bid - 1024) >> 3; bx = i >> 2; by = x * 4 + (i & 3); }

    const float* A = isQ ? queries : inputs;
    const u16* W = w_in_b + (isQ ? 0 : (size_t)E_DIM * E_DIM);
    const float* bias = b_in + (isQ ? 0 : E_DIM);
    const int m_blk = by * 128;
    const int n_blk = bx * 128;
    const int K = E_DIM;

    const int tid = threadIdx.x;
    const int l = tid & 63;
    const int w = tid >> 6;
    const int m0 = (w & 1) * 64;
    const int n0 = (w >> 1) * 64;
    const int quad = l >> 4;
    const int c = l & 15;

    f32x4 acc[4][4];
    #pragma unroll
    for (int i = 0; i < 4; ++i)
        #pragma unroll
        for (int j = 0; j < 4; ++j)
            acc[i][j] = (f32x4){0.f, 0.f, 0.f, 0.f};

    const int srow = l >> 2;            // 0..15
    const int skoff = (l & 3) * 8;      // col-block of 8 within a 32-col half
    // A: fp32 source, same (row, col-block) geometry as the old async16 path
    const float* Ag = A + (size_t)(m_blk + w * 32 + srow) * K + skoff;
    const u16*   Wg = W + (size_t)(n_blk + w * 32 + srow) * K + skoff;

    // A-register tile: [hf][t] -> 2 x f32x4 (8 fp32 = one 16B LDS slot)
    f32x4 ar[8];
    auto loadA = [&](int k0) {
        #pragma unroll
        for (int hf = 0; hf < 2; ++hf)
            #pragma unroll
            for (int t = 0; t < 2; ++t) {
                const float* p = Ag + (size_t)t * 16 * K + k0 + hf * 32;
                ar[(hf * 2 + t) * 2 + 0] = *(const f32x4*)p;
                ar[(hf * 2 + t) * 2 + 1] = *(const f32x4*)(p + 4);
            }
    };
    auto writeA = [&]() {
        #pragma unroll
        for (int hf = 0; hf < 2; ++hf)
            #pragma unroll
            for (int t = 0; t < 2; ++t) {
                bf16x8 pk = pk8(ar[(hf * 2 + t) * 2 + 0],
                                ar[(hf * 2 + t) * 2 + 1]);
                *(bf16x8*)&As[hf][(size_t)(w * 32 + t * 16) * 32 + l * 8] = pk;
            }
    };

    loadA(0);
    for (int k0 = 0; k0 < K; k0 += 64) {
        __syncthreads();                 // previous compute done; As/Ws free
        #pragma unroll
        for (int hf = 0; hf < 2; ++hf)
            #pragma unroll
            for (int t = 0; t < 2; ++t) {
                const size_t soff = (size_t)t * 16 * K + k0 + hf * 32;
                const size_t doff = (size_t)(w * 32 + t * 16) * 32;
                async16(Wg + soff, &Ws[hf][0] + doff);
            }
        writeA();                        // cvt + ds_write (A loads landed)
        __syncthreads();                 // drain W asyncs + A ds_writes
        if (k0 + 64 < K) loadA(k0 + 64); // issue next A tile; hides under MFMA

        #pragma unroll
        for (int hf = 0; hf < 2; ++hf) {
            bf16x8 af[4], wf[4];
            #pragma unroll
            for (int t = 0; t < 4; ++t) {
                af[t] = *(const bf16x8*)&As[hf][(m0 + t * 16 + c) * 32 + quad * 8];
                wf[t] = *(const bf16x8*)&Ws[hf][(n0 + t * 16 + c) * 32 + quad * 8];
            }
            #pragma unroll
            for (int i = 0; i < 4; ++i)
                #pragma unroll
                for (int j = 0; j < 4; ++j)
                    acc[i][j] = __builtin_amdgcn_mfma_f32_16x16x32_bf16(
                        af[i], wf[j], acc[i][j], 0, 0, 0);
        }
    }

    #pragma unroll
    for (int jj = 0; jj < 4; ++jj) {
        int col = n_blk + n0 + jj * 16 + c;
        float bv = bias[col];
        if (isQ || col < 1024) {
            u16* dst = isQ ? Qf : Kf;
            int hh = col >> 6, d = col & 63;
            int dq = d >> 3, dj = d & 7;
            #pragma unroll
            for (int i = 0; i < 4; ++i) {
                int t = (m_blk + m0 + i * 16) >> 4;
                size_t base = ((size_t)(t * NH + hh)) * 1024
                            + (size_t)(dq * 16 + quad * 4) * 8 + dj;
                #pragma unroll
                for (int r = 0; r < 4; ++r)
                    dst[base + (size_t)r * 8] = f2bf(acc[i][jj][r] + bv);
            }
        } else {
            int vcol = col - 1024;
            int hv = vcol >> 6, d = vcol & 63;
            int td = d >> 4, ct = d & 15;
            #pragma unroll
            for (int i = 0; i < 4; ++i) {
                int tok = m_blk + m0 + i * 16;
                int g32 = tok >> 5;
                int jo = (tok & 16) >> 2;          // 0 or 4
                ushort4 pk;
                pk.x = f2bf(acc[i][jj][0] + bv);
                pk.y = f2bf(acc[i][jj][1] + bv);
                pk.z = f2bf(acc[i][jj][2] + bv);
                pk.w = f2bf(acc[i][jj][3] + bv);
                *(ushort4*)(Vf + ((size_t)(g32 * NH + hv)) * 2048
                            + (size_t)((td * 4 + quad) * 16 + ct) * 8 + jo) = pk;
            }
        }
    }
}

// ---------------------------------------------------------------------------
// Attention.  (verbatim round-9: block-level LDS staging of K/V, T3-minimum
// schedule, defer-max, deferred-l, cvt_pk pack, setprio)
// ---------------------------------------------------------------------------
__global__ __launch_bounds__(256) void attn_kernel(
    const u16* __restrict__ Qf, const u16* __restrict__ Kf,
    const u16* __restrict__ Vf, u16* __restrict__ Ob)
{
    __shared__ u16 Ks[2][4096];
    __shared__ u16 Vs[2][4096];

    const int tid = threadIdx.x;
    const int l = tid & 63;
    const int w = tid >> 6;
    const int quad = l >> 4;
    const int c = l & 15;
    const int bid = blockIdx.x;
    const int h = bid & 15;
    const int b = (bid >> 4) & 7;
    const int qt = bid >> 7;
    const int q0 = b * LQ + qt * 64 + w * 16;
    const float C1 = 0.18033688011112042f;   // (1/8)*log2(e)
    const float THR = 8.0f;                  // defer-max threshold

    bf16x8 qf[2];
    {
        size_t qb = ((size_t)((q0 >> 4) * NH + h)) * 1024 + (size_t)l * 8;
        qf[0] = *(const bf16x8*)(Qf + qb);
        qf[1] = *(const bf16x8*)(Qf + qb + 512);
    }

    f32x4 o[4];
    #pragma unroll
    for (int td = 0; td < 4; ++td) o[td] = (f32x4){0.f, 0.f, 0.f, 0.f};
    float m_i = -1e30f;
    float lpart = 0.f;

    auto stage = [&](int buf, int kv0) {
        const int kvg = b * LKV + kv0;
        const int t16 = kvg >> 4;
        const int t32 = kvg >> 5;
        #pragma unroll
        for (int r = 0; r < 2; ++r) {
            const int nt = 2 * r + (w >> 1);
            const u16* ksrc = Kf + ((size_t)((t16 + nt) * NH + h)) * 1024
                            + (w & 1) * 512 + l * 8;
            async16(ksrc, &Ks[buf][r * 2048 + w * 512 + l * 8]);
            const u16* vsrc = Vf + ((size_t)((t32 + r) * NH + h)) * 2048
                            + w * 512 + l * 8;
            async16(vsrc, &Vs[buf][r * 2048 + w * 512 + l * 8]);
        }
    };

    auto step_lds = [&](int buf) {
        f32x4 s[4];
        #pragma unroll
        for (int nt = 0; nt < 4; ++nt) s[nt] = (f32x4){0.f, 0.f, 0.f, 0.f};
        __builtin_amdgcn_s_setprio(1);
        #pragma unroll
        for (int nt = 0; nt < 4; ++nt)
            #pragma unroll
            for (int hk = 0; hk < 2; ++hk) {
                bf16x8 kf = *(const bf16x8*)&Ks[buf][nt * 1024 + hk * 512 + l * 8];
                s[nt] = __builtin_amdgcn_mfma_f32_16x16x32_bf16(
                    kf, qf[hk], s[nt], 0, 0, 0);
            }
        __builtin_amdgcn_s_setprio(0);

        float m01 = fmaxf(fmaxf(s[0][0], s[0][1]), fmaxf(s[0][2], s[0][3]));
        float m23 = fmaxf(fmaxf(s[1][0], s[1][1]), fmaxf(s[1][2], s[1][3]));
        float m45 = fmaxf(fmaxf(s[2][0], s[2][1]), fmaxf(s[2][2], s[2][3]));
        float m67 = fmaxf(fmaxf(s[3][0], s[3][1]), fmaxf(s[3][2], s[3][3]));
        float vml = fmaxf(fmaxf(m01, m23), fmaxf(m45, m67));

        if (!__all(vml - m_i <= THR)) {
            float vmr = vml;
            vmr = fmaxf(vmr, __shfl_xor(vmr, 16, 64));
            vmr = fmaxf(vmr, __shfl_xor(vmr, 32, 64));
            float mnew = fmaxf(m_i, vmr);
            float alpha = __builtin_amdgcn_exp2f((m_i - mnew) * C1);
            m_i = mnew;
            lpart *= alpha;
            float ar_[4];
            #pragma unroll
            for (int r = 0; r < 4; ++r) ar_[r] = __shfl(alpha, quad * 4 + r, 16);
            #pragma unroll
            for (int td = 0; td < 4; ++td)
                #pragma unroll
                for (int r = 0; r < 4; ++r) o[td][r] *= ar_[r];
        }

        float p[4][4];
        float rs = 0.f;
        #pragma unroll
        for (int nt = 0; nt < 4; ++nt)
            #pragma unroll
            for (int r = 0; r < 4; ++r) {
                p[nt][r] = __builtin_amdgcn_exp2f((s[nt][r] - m_i) * C1);
                rs += p[nt][r];
            }
        lpart += rs;

        bf16x8 af[2];
        #pragma unroll
        for (int g = 0; g < 2; ++g) {
            union { unsigned u[4]; bf16x8 v; } r_;
            r_.u[0] = pk2(p[2 * g][0],     p[2 * g][1]);
            r_.u[1] = pk2(p[2 * g][2],     p[2 * g][3]);
            r_.u[2] = pk2(p[2 * g + 1][0], p[2 * g + 1][1]);
            r_.u[3] = pk2(p[2 * g + 1][2], p[2 * g + 1][3]);
            af[g] = r_.v;
        }

        __builtin_amdgcn_s_setprio(1);
        #pragma unroll
        for (int g = 0; g < 2; ++g)
            #pragma unroll
            for (int td = 0; td < 4; ++td) {
                bf16x8 vf = *(const bf16x8*)&Vs[buf][g * 2048 + td * 512 + l * 8];
                o[td] = __builtin_amdgcn_mfma_f32_16x16x32_bf16(
                    af[g], vf, o[td], 0, 0, 0);
            }
        __builtin_amdgcn_s_setprio(0);
    };

    stage(0, 0);
    __syncthreads();
    int cur = 0;
    #pragma unroll 2
    for (int it = 0; it < 16; ++it) {
        if (it < 15) stage(cur ^ 1, (it + 1) * 64);
        step_lds(cur);
        __syncthreads();
        cur ^= 1;
    }

    float l_i = lpart;
    l_i += __shfl_xor(l_i, 16, 64);
    l_i += __shfl_xor(l_i, 32, 64);
    float invl = 1.f / l_i;
    float ir[4];
    #pragma unroll
    for (int r = 0; r < 4; ++r) ir[r] = __shfl(invl, quad * 4 + r, 16);
    #pragma unroll
    for (int td = 0; td < 4; ++td)
        #pragma unroll
        for (int r = 0; r < 4; ++r)
            Ob[(size_t)(q0 + quad * 4 + r) * E_DIM + h * 64 + td * 16 + c] =
                f2bf(o[td][r] * ir[r]);
}

// ---------------------------------------------------------------------------
// Output projection: out[4096,1024] = Ob @ w_out^T + b_out (fp32 out).
// (verbatim round-8/9: 64x64 tiles, grid 1024, swapped operands/float4)
// ---------------------------------------------------------------------------
__global__ __launch_bounds__(256) void out_gemm_kernel(
    const u16* __restrict__ A, const u16* __restrict__ W,
    const float* __restrict__ bias, float* __restrict__ Cf)
{
    __shared__ u16 As[2][64 * 32];
    __shared__ u16 Ws[2][64 * 32];

    const int K = E_DIM, N = E_DIM;
    const int bid = blockIdx.x;
    const int x = bid & 7;
    const int i_ = bid >> 3;            // 0..127
    const int m_blk = (x * 8 + (i_ & 7)) * 64;   // 64 m-blocks
    const int n_blk = (i_ >> 3) * 64;            // 16 n-blocks

    const int tid = threadIdx.x;
    const int l = tid & 63;
    const int w = tid >> 6;
    const int m0 = (w & 1) * 32;
    const int n0 = (w >> 1) * 32;
    const int quad = l >> 4;
    const int c = l & 15;

    f32x4 acc[2][2];
    #pragma unroll
    for (int i = 0; i < 2; ++i)
        #pragma unroll
        for (int j = 0; j < 2; ++j)
            acc[i][j] = (f32x4){0.f, 0.f, 0.f, 0.f};

    const int srow = l >> 2;            // 0..15
    const int skoff = (l & 3) * 8;
    const u16* Ag = A + (size_t)(m_blk + w * 16 + srow) * K + skoff;
    const u16* Wg = W + (size_t)(n_blk + w * 16 + srow) * K + skoff;

    for (int k0 = 0; k0 < K; k0 += 64) {
        __syncthreads();
        #pragma unroll
        for (int hf = 0; hf < 2; ++hf) {
            const size_t soff = (size_t)(k0 + hf * 32);
            const size_t doff = (size_t)(w * 16) * 32;
            async16(Ag + soff, &As[hf][0] + doff);
            async16(Wg + soff, &Ws[hf][0] + doff);
        }
        __syncthreads();

        #pragma unroll
        for (int hf = 0; hf < 2; ++hf) {
            bf16x8 af[2], wf[2];
            #pragma unroll
            for (int t = 0; t < 2; ++t) {
                af[t] = *(const bf16x8*)&As[hf][(m0 + t * 16 + c) * 32 + quad * 8];
                wf[t] = *(const bf16x8*)&Ws[hf][(n0 + t * 16 + c) * 32 + quad * 8];
            }
            #pragma unroll
            for (int i = 0; i < 2; ++i)
                #pragma unroll
                for (int j = 0; j < 2; ++j)
                    acc[i][j] = __builtin_amdgcn_mfma_f32_16x16x32_bf16(
                        wf[j], af[i], acc[i][j], 0, 0, 0);
        }
    }

    #pragma unroll
    for (int j = 0; j < 2; ++j) {
        const int colb = n_blk + n0 + j * 16 + quad * 4;
        const float4 bv = *(const float4*)&bias[colb];
        #pragma unroll
        for (int i = 0; i < 2; ++i) {
            const int row = m_blk + m0 + i * 16 + c;
            float4 o4;
            o4.x = acc[i][j][0] + bv.x;
            o4.y = acc[i][j][1] + bv.y;
            o4.z = acc[i][j][2] + bv.z;
            o4.w = acc[i][j][3] + bv.w;
            *(float4*)&Cf[(size_t)row * N + colb] = o4;
        }
    }
}

// ---------------------------------------------------------------------------
extern "C" void kernel_launch(void* const* d_in, const int* in_sizes, int n_in,
                              void* d_out, int out_size, void* d_ws, size_t ws_size,
                              hipStream_t stream) {
    const float* inputs  = (const float*)d_in[0];   // [8192,1024]
    const float* queries = (const float*)d_in[1];   // [4096,1024]
    const float* w_in    = (const float*)d_in[2];   // [3072,1024]
    const float* b_in    = (const float*)d_in[3];   // [3072]
    const float* w_out   = (const float*)d_in[4];   // [1024,1024]
    const float* b_out   = (const float*)d_in[5];   // [1024]
    float* out = (float*)d_out;                     // [4096,1024] fp32

    const int NQ = BSEG * LQ;    // 4096
    const int NKV = BSEG * LKV;  // 8192

    // workspace: 56 MB (no inputs/queries mirrors anymore)
    u16* w_in_b  = (u16*)d_ws;                                 //  6 MB
    u16* w_out_b = w_in_b  + (size_t)3 * E_DIM * E_DIM;        //  2 MB
    u16* Qf      = w_out_b + (size_t)E_DIM * E_DIM;            //  8 MB
    u16* Kf      = Qf      + (size_t)NQ * E_DIM;               // 16 MB
    u16* Vf      = Kf      + (size_t)NKV * E_DIM;              // 16 MB
    u16* Ob      = Vf      + (size_t)NKV * E_DIM;              //  8 MB

    dim3 blk(256);

    cvt_w_kernel<<<4096, blk, 0, stream>>>(
        w_in, w_out, w_in_b, w_out_b);

    proj_gemm_kernel<<<1280, blk, 0, stream>>>(
        inputs, queries, w_in_b, b_in, Kf, Qf, Vf);

    attn_kernel<<<1024, blk, 0, stream>>>(Qf, Kf, Vf, Ob);

    out_gemm_kernel<<<1024, blk, 0, stream>>>(
        Ob, w_out_b, b_out, out);
}

// Round 11
// 216.847 us; speedup vs baseline: 2.4537x; 2.4537x over previous
//
#include <hip/hip_runtime.h>

#define E_DIM 1024
#define NH 16
#define DH 64
#define BSEG 8
#define LQ 512
#define LKV 1024

typedef short bf16x8 __attribute__((ext_vector_type(8)));
typedef float f32x4 __attribute__((ext_vector_type(4)));
typedef unsigned short u16;

// round-to-nearest-even fp32 -> bf16 bits
__device__ __forceinline__ u16 f2bf(float x) {
    unsigned u = __float_as_uint(x);
    u += 0x7FFF + ((u >> 16) & 1);
    return (u16)(u >> 16);
}

// async global->LDS, 16B per lane; lds dest wave-uniform base + lane*16
__device__ __forceinline__ void async16(const void* g, const void* l) {
    __builtin_amdgcn_global_load_lds(
        (const __attribute__((address_space(1))) unsigned int*)g,
        (__attribute__((address_space(3))) unsigned int*)l, 16, 0, 0);
}

// packed RNE f32->bf16 pair -> one u32 (v_cvt_pk_bf16_f32)
__device__ __forceinline__ unsigned pk2(float a, float b) {
    unsigned r;
    asm("v_cvt_pk_bf16_f32 %0, %1, %2" : "=v"(r) : "v"(a), "v"(b));
    return r;
}

// ---------------------------------------------------------------------------
// Fused fp32->bf16 convert for all 4 inputs (one launch).  (verbatim r0-r9)
// NOTE: three attempts to remove this kernel (cvt-on-read r2, fp32-A
// reg-staging r10) all lost — proj has no VGPR headroom under (256,5).
// ---------------------------------------------------------------------------
__global__ __launch_bounds__(256) void cvt_all_kernel(
    const float* __restrict__ inputs, const float* __restrict__ queries,
    const float* __restrict__ w_in, const float* __restrict__ w_out,
    u16* __restrict__ ib, u16* __restrict__ qb,
    u16* __restrict__ wib, u16* __restrict__ wob)
{
    int blk = blockIdx.x;
    const float* s; u16* d; int base;
    if (blk < 8192)        { s = inputs;  d = ib;  base = blk; }
    else if (blk < 12288)  { s = queries; d = qb;  base = blk - 8192; }
    else if (blk < 15360)  { s = w_in;    d = wib; base = blk - 12288; }
    else                   { s = w_out;   d = wob; base = blk - 15360; }
    int i = base * 256 + threadIdx.x;
    float4 v = ((const float4*)s)[i];
    ushort4 o;
    o.x = f2bf(v.x); o.y = f2bf(v.y); o.z = f2bf(v.z); o.w = f2bf(v.w);
    ((ushort4*)d)[i] = o;
}

// ---------------------------------------------------------------------------
// Fused Q/K/V projection GEMM.  (verbatim round-8/9: 60-62 µs, VGPR 48,
// AGPR-resident accumulators, no spill.  The (256,5) cap leaves ZERO
// register headroom — acc uses 64 AGPR of the unified file.  Do not add
// live state (r7 swap-epilogue spill, r10 fp32-A spill).)
// ---------------------------------------------------------------------------
__global__ __launch_bounds__(256, 5) void proj_gemm_kernel(
    const u16* __restrict__ inputs_b, const u16* __restrict__ queries_b,
    const u16* __restrict__ w_in_b, const float* __restrict__ b_in,
    u16* __restrict__ Kf, u16* __restrict__ Qf, u16* __restrict__ Vf)
{
    __shared__ u16 As[2][128 * 32];
    __shared__ u16 Ws[2][128 * 32];

    const int bid = blockIdx.x;
    const bool isQ = (bid >= 1024);
    const int x = bid & 7;
    int bx, by;
    if (!isQ) { int i = bid >> 3;          bx = i >> 3; by = x * 8 + (i & 7); }
    else      { int i = (bid - 1024) >> 3; bx = i >> 2; by = x * 4 + (i & 3); }

    const u16* A = isQ ? queries_b : inputs_b;
    const u16* W = w_in_b + (isQ ? 0 : (size_t)E_DIM * E_DIM);
    const float* bias = b_in + (isQ ? 0 : E_DIM);
    const int m_blk = by * 128;
    const int n_blk = bx * 128;
    const int K = E_DIM;

    const int tid = threadIdx.x;
    const int l = tid & 63;
    const int w = tid >> 6;
    const int m0 = (w & 1) * 64;
    const int n0 = (w >> 1) * 64;
    const int quad = l >> 4;
    const int c = l & 15;

    f32x4 acc[4][4];
    #pragma unroll
    for (int i = 0; i < 4; ++i)
        #pragma unroll
        for (int j = 0; j < 4; ++j)
            acc[i][j] = (f32x4){0.f, 0.f, 0.f, 0.f};

    const int srow = l >> 2;            // 0..15
    const int skoff = (l & 3) * 8;      // u16 col within a 32-col half
    const u16* Ag = A + (size_t)(m_blk + w * 32 + srow) * K + skoff;
    const u16* Wg = W + (size_t)(n_blk + w * 32 + srow) * K + skoff;

    for (int k0 = 0; k0 < K; k0 += 64) {
        __syncthreads();
        #pragma unroll
        for (int hf = 0; hf < 2; ++hf)
            #pragma unroll
            for (int t = 0; t < 2; ++t) {
                const size_t soff = (size_t)t * 16 * K + k0 + hf * 32;
                const size_t doff = (size_t)(w * 32 + t * 16) * 32;
                async16(Ag + soff, &As[hf][0] + doff);
                async16(Wg + soff, &Ws[hf][0] + doff);
            }
        __syncthreads();

        #pragma unroll
        for (int hf = 0; hf < 2; ++hf) {
            bf16x8 af[4], wf[4];
            #pragma unroll
            for (int t = 0; t < 4; ++t) {
                af[t] = *(const bf16x8*)&As[hf][(m0 + t * 16 + c) * 32 + quad * 8];
                wf[t] = *(const bf16x8*)&Ws[hf][(n0 + t * 16 + c) * 32 + quad * 8];
            }
            #pragma unroll
            for (int i = 0; i < 4; ++i)
                #pragma unroll
                for (int j = 0; j < 4; ++j)
                    acc[i][j] = __builtin_amdgcn_mfma_f32_16x16x32_bf16(
                        af[i], wf[j], acc[i][j], 0, 0, 0);
        }
    }

    #pragma unroll
    for (int jj = 0; jj < 4; ++jj) {
        int col = n_blk + n0 + jj * 16 + c;
        float bv = bias[col];
        if (isQ || col < 1024) {
            u16* dst = isQ ? Qf : Kf;
            int hh = col >> 6, d = col & 63;
            int dq = d >> 3, dj = d & 7;
            #pragma unroll
            for (int i = 0; i < 4; ++i) {
                int t = (m_blk + m0 + i * 16) >> 4;
                size_t base = ((size_t)(t * NH + hh)) * 1024
                            + (size_t)(dq * 16 + quad * 4) * 8 + dj;
                #pragma unroll
                for (int r = 0; r < 4; ++r)
                    dst[base + (size_t)r * 8] = f2bf(acc[i][jj][r] + bv);
            }
        } else {
            int vcol = col - 1024;
            int hv = vcol >> 6, d = vcol & 63;
            int td = d >> 4, ct = d & 15;
            #pragma unroll
            for (int i = 0; i < 4; ++i) {
                int tok = m_blk + m0 + i * 16;
                int g32 = tok >> 5;
                int jo = (tok & 16) >> 2;          // 0 or 4
                ushort4 pk;
                pk.x = f2bf(acc[i][jj][0] + bv);
                pk.y = f2bf(acc[i][jj][1] + bv);
                pk.z = f2bf(acc[i][jj][2] + bv);
                pk.w = f2bf(acc[i][jj][3] + bv);
                *(ushort4*)(Vf + ((size_t)(g32 * NH + hv)) * 2048
                            + (size_t)((td * 4 + quad) * 16 + ct) * 8 + jo) = pk;
            }
        }
    }
}

// ---------------------------------------------------------------------------
// Attention.  Round-11: round-9's LDS K/V staging PLUS the round-6
// cross-step pipeline re-added: qk(t) (pure MFMA, reads just-landed K tile)
// is issued BEFORE smpv(t-1) (VALU-heavy softmax + PV) — independent
// dataflow, compiler co-schedules across the MFMA/VALU pipes.
// V triple-buffered (tile must survive one extra step); LDS = 40 KB,
// 4 blocks/CU = 160 KB exactly.  S double-buffered in regs, all indices
// compile-time via full unroll (rule #20).  Per-tile op order unchanged
// -> bit-identical numerics.
// ---------------------------------------------------------------------------
__global__ __launch_bounds__(256) void attn_kernel(
    const u16* __restrict__ Qf, const u16* __restrict__ Kf,
    const u16* __restrict__ Vf, u16* __restrict__ Ob)
{
    __shared__ u16 Ks[2][4096];
    __shared__ u16 Vs[3][4096];

    const int tid = threadIdx.x;
    const int l = tid & 63;
    const int w = tid >> 6;
    const int quad = l >> 4;
    const int c = l & 15;
    const int bid = blockIdx.x;
    const int h = bid & 15;
    const int b = (bid >> 4) & 7;
    const int qt = bid >> 7;
    const int q0 = b * LQ + qt * 64 + w * 16;
    const float C1 = 0.18033688011112042f;   // (1/8)*log2(e)
    const float THR = 8.0f;                  // defer-max threshold

    bf16x8 qf[2];
    {
        size_t qb = ((size_t)((q0 >> 4) * NH + h)) * 1024 + (size_t)l * 8;
        qf[0] = *(const bf16x8*)(Qf + qb);
        qf[1] = *(const bf16x8*)(Qf + qb + 512);
    }

    f32x4 o[4];
    #pragma unroll
    for (int td = 0; td < 4; ++td) o[td] = (f32x4){0.f, 0.f, 0.f, 0.f};
    float m_i = -1e30f;
    float lpart = 0.f;

    auto stage = [&](int kb, int vb, int kv0) {
        const int kvg = b * LKV + kv0;
        const int t16 = kvg >> 4;
        const int t32 = kvg >> 5;
        #pragma unroll
        for (int r = 0; r < 2; ++r) {
            const int nt = 2 * r + (w >> 1);
            const u16* ksrc = Kf + ((size_t)((t16 + nt) * NH + h)) * 1024
                            + (w & 1) * 512 + l * 8;
            async16(ksrc, &Ks[kb][r * 2048 + w * 512 + l * 8]);
            const u16* vsrc = Vf + ((size_t)((t32 + r) * NH + h)) * 2048
                            + w * 512 + l * 8;
            async16(vsrc, &Vs[vb][r * 2048 + w * 512 + l * 8]);
        }
    };

    // QK^T MFMA cluster: reads K tile from LDS, writes S regs.
    auto qk = [&](const u16* Kbuf, f32x4* s) {
        #pragma unroll
        for (int nt = 0; nt < 4; ++nt) s[nt] = (f32x4){0.f, 0.f, 0.f, 0.f};
        __builtin_amdgcn_s_setprio(1);
        #pragma unroll
        for (int nt = 0; nt < 4; ++nt)
            #pragma unroll
            for (int hk = 0; hk < 2; ++hk) {
                bf16x8 kf = *(const bf16x8*)&Kbuf[nt * 1024 + hk * 512 + l * 8];
                s[nt] = __builtin_amdgcn_mfma_f32_16x16x32_bf16(
                    kf, qf[hk], s[nt], 0, 0, 0);
            }
        __builtin_amdgcn_s_setprio(0);
    };

    // softmax (defer-max) + PV for one tile (S regs + V tile from LDS).
    auto smpv = [&](f32x4* s, const u16* Vbuf) {
        float m01 = fmaxf(fmaxf(s[0][0], s[0][1]), fmaxf(s[0][2], s[0][3]));
        float m23 = fmaxf(fmaxf(s[1][0], s[1][1]), fmaxf(s[1][2], s[1][3]));
        float m45 = fmaxf(fmaxf(s[2][0], s[2][1]), fmaxf(s[2][2], s[2][3]));
        float m67 = fmaxf(fmaxf(s[3][0], s[3][1]), fmaxf(s[3][2], s[3][3]));
        float vml = fmaxf(fmaxf(m01, m23), fmaxf(m45, m67));

        if (!__all(vml - m_i <= THR)) {
            float vmr = vml;
            vmr = fmaxf(vmr, __shfl_xor(vmr, 16, 64));
            vmr = fmaxf(vmr, __shfl_xor(vmr, 32, 64));
            float mnew = fmaxf(m_i, vmr);
            float alpha = __builtin_amdgcn_exp2f((m_i - mnew) * C1);
            m_i = mnew;
            lpart *= alpha;
            float ar_[4];
            #pragma unroll
            for (int r = 0; r < 4; ++r) ar_[r] = __shfl(alpha, quad * 4 + r, 16);
            #pragma unroll
            for (int td = 0; td < 4; ++td)
                #pragma unroll
                for (int r = 0; r < 4; ++r) o[td][r] *= ar_[r];
        }

        float p[4][4];
        float rs = 0.f;
        #pragma unroll
        for (int nt = 0; nt < 4; ++nt)
            #pragma unroll
            for (int r = 0; r < 4; ++r) {
                p[nt][r] = __builtin_amdgcn_exp2f((s[nt][r] - m_i) * C1);
                rs += p[nt][r];
            }
        lpart += rs;

        bf16x8 af[2];
        #pragma unroll
        for (int g = 0; g < 2; ++g) {
            union { unsigned u[4]; bf16x8 v; } r_;
            r_.u[0] = pk2(p[2 * g][0],     p[2 * g][1]);
            r_.u[1] = pk2(p[2 * g][2],     p[2 * g][3]);
            r_.u[2] = pk2(p[2 * g + 1][0], p[2 * g + 1][1]);
            r_.u[3] = pk2(p[2 * g + 1][2], p[2 * g + 1][3]);
            af[g] = r_.v;
        }

        __builtin_amdgcn_s_setprio(1);
        #pragma unroll
        for (int g = 0; g < 2; ++g)
            #pragma unroll
            for (int td = 0; td < 4; ++td) {
                bf16x8 vf = *(const bf16x8*)&Vbuf[g * 2048 + td * 512 + l * 8];
                o[td] = __builtin_amdgcn_mfma_f32_16x16x32_bf16(
                    af[g], vf, o[td], 0, 0, 0);
            }
        __builtin_amdgcn_s_setprio(0);
    };

    // Pipeline:
    //   iter t: barrier(stage(t) landed) -> issue stage(t+1)
    //           -> qk(t) [MFMA] -> smpv(t-1) [VALU+MFMA]  (independent)
    // Hazards: stage(t+1) overwrites Ks[(t-1)&1] (read at iter t-1, barrier-
    // separated) and Vs[(t+1)%3] (tile t-2, consumed at iter t-1).
    f32x4 sA[4], sB[4];
    stage(0, 0, 0);
    __syncthreads();
    stage(1, 1, 64);
    qk(Ks[0], sA);
    #pragma unroll
    for (int t = 1; t < 16; ++t) {
        __syncthreads();                       // stage(t) landed
        if (t < 15) stage((t + 1) & 1, (t + 1) % 3, (t + 1) * 64);
        if (t & 1) { qk(Ks[1], sB); smpv(sA, Vs[(t - 1) % 3]); }
        else       { qk(Ks[0], sA); smpv(sB, Vs[(t - 1) % 3]); }
    }
    smpv(sB, Vs[0]);                           // tile 15 (staged into Vs[0])

    // epilogue: finish deferred l reduction, normalize
    float l_i = lpart;
    l_i += __shfl_xor(l_i, 16, 64);
    l_i += __shfl_xor(l_i, 32, 64);
    float invl = 1.f / l_i;
    float ir[4];
    #pragma unroll
    for (int r = 0; r < 4; ++r) ir[r] = __shfl(invl, quad * 4 + r, 16);
    #pragma unroll
    for (int td = 0; td < 4; ++td)
        #pragma unroll
        for (int r = 0; r < 4; ++r)
            Ob[(size_t)(q0 + quad * 4 + r) * E_DIM + h * 64 + td * 16 + c] =
                f2bf(o[td][r] * ir[r]);
}

// ---------------------------------------------------------------------------
// Output projection: out[4096,1024] = Ob @ w_out^T + b_out (fp32 out).
// (verbatim round-8/9: 64x64 tiles, grid 1024, swapped operands/float4)
// ---------------------------------------------------------------------------
__global__ __launch_bounds__(256) void out_gemm_kernel(
    const u16* __restrict__ A, const u16* __restrict__ W,
    const float* __restrict__ bias, float* __restrict__ Cf)
{
    __shared__ u16 As[2][64 * 32];
    __shared__ u16 Ws[2][64 * 32];

    const int K = E_DIM, N = E_DIM;
    const int bid = blockIdx.x;
    const int x = bid & 7;
    const int i_ = bid >> 3;            // 0..127
    const int m_blk = (x * 8 + (i_ & 7)) * 64;   // 64 m-blocks
    const int n_blk = (i_ >> 3) * 64;            // 16 n-blocks

    const int tid = threadIdx.x;
    const int l = tid & 63;
    const int w = tid >> 6;
    const int m0 = (w & 1) * 32;
    const int n0 = (w >> 1) * 32;
    const int quad = l >> 4;
    const int c = l & 15;

    f32x4 acc[2][2];
    #pragma unroll
    for (int i = 0; i < 2; ++i)
        #pragma unroll
        for (int j = 0; j < 2; ++j)
            acc[i][j] = (f32x4){0.f, 0.f, 0.f, 0.f};

    const int srow = l >> 2;            // 0..15
    const int skoff = (l & 3) * 8;
    const u16* Ag = A + (size_t)(m_blk + w * 16 + srow) * K + skoff;
    const u16* Wg = W + (size_t)(n_blk + w * 16 + srow) * K + skoff;

    for (int k0 = 0; k0 < K; k0 += 64) {
        __syncthreads();
        #pragma unroll
        for (int hf = 0; hf < 2; ++hf) {
            const size_t soff = (size_t)(k0 + hf * 32);
            const size_t doff = (size_t)(w * 16) * 32;
            async16(Ag + soff, &As[hf][0] + doff);
            async16(Wg + soff, &Ws[hf][0] + doff);
        }
        __syncthreads();

        #pragma unroll
        for (int hf = 0; hf < 2; ++hf) {
            bf16x8 af[2], wf[2];
            #pragma unroll
            for (int t = 0; t < 2; ++t) {
                af[t] = *(const bf16x8*)&As[hf][(m0 + t * 16 + c) * 32 + quad * 8];
                wf[t] = *(const bf16x8*)&Ws[hf][(n0 + t * 16 + c) * 32 + quad * 8];
            }
            #pragma unroll
            for (int i = 0; i < 2; ++i)
                #pragma unroll
                for (int j = 0; j < 2; ++j)
                    acc[i][j] = __builtin_amdgcn_mfma_f32_16x16x32_bf16(
                        wf[j], af[i], acc[i][j], 0, 0, 0);
        }
    }

    #pragma unroll
    for (int j = 0; j < 2; ++j) {
        const int colb = n_blk + n0 + j * 16 + quad * 4;
        const float4 bv = *(const float4*)&bias[colb];
        #pragma unroll
        for (int i = 0; i < 2; ++i) {
            const int row = m_blk + m0 + i * 16 + c;
            float4 o4;
            o4.x = acc[i][j][0] + bv.x;
            o4.y = acc[i][j][1] + bv.y;
            o4.z = acc[i][j][2] + bv.z;
            o4.w = acc[i][j][3] + bv.w;
            *(float4*)&Cf[(size_t)row * N + colb] = o4;
        }
    }
}

// ---------------------------------------------------------------------------
extern "C" void kernel_launch(void* const* d_in, const int* in_sizes, int n_in,
                              void* d_out, int out_size, void* d_ws, size_t ws_size,
                              hipStream_t stream) {
    const float* inputs  = (const float*)d_in[0];   // [8192,1024]
    const float* queries = (const float*)d_in[1];   // [4096,1024]
    const float* w_in    = (const float*)d_in[2];   // [3072,1024]
    const float* b_in    = (const float*)d_in[3];   // [3072]
    const float* w_out   = (const float*)d_in[4];   // [1024,1024]
    const float* b_out   = (const float*)d_in[5];   // [1024]
    float* out = (float*)d_out;                     // [4096,1024] fp32

    const int NQ = BSEG * LQ;    // 4096
    const int NKV = BSEG * LKV;  // 8192

    // workspace: 80 MB
    u16* inputs_b  = (u16*)d_ws;                                   // 16 MB
    u16* queries_b = inputs_b  + (size_t)NKV * E_DIM;              //  8 MB
    u16* w_in_b    = queries_b + (size_t)NQ * E_DIM;               //  6 MB
    u16* w_out_b   = w_in_b    + (size_t)3 * E_DIM * E_DIM;        //  2 MB
    u16* Qf        = w_out_b   + (size_t)E_DIM * E_DIM;            //  8 MB
    u16* Kf        = Qf        + (size_t)NQ * E_DIM;               // 16 MB
    u16* Vf        = Kf        + (size_t)NKV * E_DIM;              // 16 MB
    u16* Ob        = Vf        + (size_t)NKV * E_DIM;              //  8 MB

    dim3 blk(256);

    cvt_all_kernel<<<16384, blk, 0, stream>>>(
        inputs, queries, w_in, w_out, inputs_b, queries_b, w_in_b, w_out_b);

    proj_gemm_kernel<<<1280, blk, 0, stream>>>(
        inputs_b, queries_b, w_in_b, b_in, Kf, Qf, Vf);

    attn_kernel<<<1024, blk, 0, stream>>>(Qf, Kf, Vf, Ob);

    out_gemm_kernel<<<1024, blk, 0, stream>>>(
        Ob, w_out_b, b_out, out);
}

// Round 14
// 211.129 us; speedup vs baseline: 2.5201x; 1.0271x over previous
//
#include <hip/hip_runtime.h>

#define E_DIM 1024
#define NH 16
#define DH 64
#define BSEG 8
#define LQ 512
#define LKV 1024

typedef short bf16x8 __attribute__((ext_vector_type(8)));
typedef float f32x4 __attribute__((ext_vector_type(4)));
typedef unsigned short u16;

// round-to-nearest-even fp32 -> bf16 bits
__device__ __forceinline__ u16 f2bf(float x) {
    unsigned u = __float_as_uint(x);
    u += 0x7FFF + ((u >> 16) & 1);
    return (u16)(u >> 16);
}

// async global->LDS, 16B per lane; lds dest wave-uniform base + lane*16
__device__ __forceinline__ void async16(const void* g, const void* l) {
    __builtin_amdgcn_global_load_lds(
        (const __attribute__((address_space(1))) unsigned int*)g,
        (__attribute__((address_space(3))) unsigned int*)l, 16, 0, 0);
}

// packed RNE f32->bf16 pair -> one u32 (v_cvt_pk_bf16_f32)
__device__ __forceinline__ unsigned pk2(float a, float b) {
    unsigned r;
    asm("v_cvt_pk_bf16_f32 %0, %1, %2" : "=v"(r) : "v"(a), "v"(b));
    return r;
}

// ---------------------------------------------------------------------------
// Fused fp32->bf16 convert for all 4 inputs (one launch).
// 16384-block one-float4-per-thread form (round-0..9, ~10 passing sessions).
// The round-12 grid-stride variant coincided with a post-timing output
// divergence; reverted on evidence.  Do not re-attempt without a
// race-screen harness.
// ---------------------------------------------------------------------------
__global__ __launch_bounds__(256) void cvt_all_kernel(
    const float* __restrict__ inputs, const float* __restrict__ queries,
    const float* __restrict__ w_in, const float* __restrict__ w_out,
    u16* __restrict__ ib, u16* __restrict__ qb,
    u16* __restrict__ wib, u16* __restrict__ wob)
{
    int blk = blockIdx.x;
    const float* s; u16* d; int base;
    if (blk < 8192)        { s = inputs;  d = ib;  base = blk; }
    else if (blk < 12288)  { s = queries; d = qb;  base = blk - 8192; }
    else if (blk < 15360)  { s = w_in;    d = wib; base = blk - 12288; }
    else                   { s = w_out;   d = wob; base = blk - 15360; }
    int i = base * 256 + threadIdx.x;
    float4 v = ((const float4*)s)[i];
    ushort4 o;
    o.x = f2bf(v.x); o.y = f2bf(v.y); o.z = f2bf(v.z); o.w = f2bf(v.w);
    ((ushort4*)d)[i] = o;
}

// ---------------------------------------------------------------------------
// Fused Q/K/V projection GEMM.  (verbatim round-8/9: 60-62 µs, VGPR 48,
// AGPR-resident accumulators, no spill.  The (256,5) cap leaves ZERO
// register headroom — acc uses 64 AGPR of the unified file.  Do not add
// live state (r7 swap-epilogue spill, r10 fp32-A spill).)
// ---------------------------------------------------------------------------
__global__ __launch_bounds__(256, 5) void proj_gemm_kernel(
    const u16* __restrict__ inputs_b, const u16* __restrict__ queries_b,
    const u16* __restrict__ w_in_b, const float* __restrict__ b_in,
    u16* __restrict__ Kf, u16* __restrict__ Qf, u16* __restrict__ Vf)
{
    __shared__ u16 As[2][128 * 32];
    __shared__ u16 Ws[2][128 * 32];

    const int bid = blockIdx.x;
    const bool isQ = (bid >= 1024);
    const int x = bid & 7;
    int bx, by;
    if (!isQ) { int i = bid >> 3;          bx = i >> 3; by = x * 8 + (i & 7); }
    else      { int i = (bid - 1024) >> 3; bx = i >> 2; by = x * 4 + (i & 3); }

    const u16* A = isQ ? queries_b : inputs_b;
    const u16* W = w_in_b + (isQ ? 0 : (size_t)E_DIM * E_DIM);
    const float* bias = b_in + (isQ ? 0 : E_DIM);
    const int m_blk = by * 128;
    const int n_blk = bx * 128;
    const int K = E_DIM;

    const int tid = threadIdx.x;
    const int l = tid & 63;
    const int w = tid >> 6;
    const int m0 = (w & 1) * 64;
    const int n0 = (w >> 1) * 64;
    const int quad = l >> 4;
    const int c = l & 15;

    f32x4 acc[4][4];
    #pragma unroll
    for (int i = 0; i < 4; ++i)
        #pragma unroll
        for (int j = 0; j < 4; ++j)
            acc[i][j] = (f32x4){0.f, 0.f, 0.f, 0.f};

    const int srow = l >> 2;            // 0..15
    const int skoff = (l & 3) * 8;      // u16 col within a 32-col half
    const u16* Ag = A + (size_t)(m_blk + w * 32 + srow) * K + skoff;
    const u16* Wg = W + (size_t)(n_blk + w * 32 + srow) * K + skoff;

    for (int k0 = 0; k0 < K; k0 += 64) {
        __syncthreads();
        #pragma unroll
        for (int hf = 0; hf < 2; ++hf)
            #pragma unroll
            for (int t = 0; t < 2; ++t) {
                const size_t soff = (size_t)t * 16 * K + k0 + hf * 32;
                const size_t doff = (size_t)(w * 32 + t * 16) * 32;
                async16(Ag + soff, &As[hf][0] + doff);
                async16(Wg + soff, &Ws[hf][0] + doff);
            }
        __syncthreads();

        #pragma unroll
        for (int hf = 0; hf < 2; ++hf) {
            bf16x8 af[4], wf[4];
            #pragma unroll
            for (int t = 0; t < 4; ++t) {
                af[t] = *(const bf16x8*)&As[hf][(m0 + t * 16 + c) * 32 + quad * 8];
                wf[t] = *(const bf16x8*)&Ws[hf][(n0 + t * 16 + c) * 32 + quad * 8];
            }
            #pragma unroll
            for (int i = 0; i < 4; ++i)
                #pragma unroll
                for (int j = 0; j < 4; ++j)
                    acc[i][j] = __builtin_amdgcn_mfma_f32_16x16x32_bf16(
                        af[i], wf[j], acc[i][j], 0, 0, 0);
        }
    }

    #pragma unroll
    for (int jj = 0; jj < 4; ++jj) {
        int col = n_blk + n0 + jj * 16 + c;
        float bv = bias[col];
        if (isQ || col < 1024) {
            u16* dst = isQ ? Qf : Kf;
            int hh = col >> 6, d = col & 63;
            int dq = d >> 3, dj = d & 7;
            #pragma unroll
            for (int i = 0; i < 4; ++i) {
                int t = (m_blk + m0 + i * 16) >> 4;
                size_t base = ((size_t)(t * NH + hh)) * 1024
                            + (size_t)(dq * 16 + quad * 4) * 8 + dj;
                #pragma unroll
                for (int r = 0; r < 4; ++r)
                    dst[base + (size_t)r * 8] = f2bf(acc[i][jj][r] + bv);
            }
        } else {
            int vcol = col - 1024;
            int hv = vcol >> 6, d = vcol & 63;
            int td = d >> 4, ct = d & 15;
            #pragma unroll
            for (int i = 0; i < 4; ++i) {
                int tok = m_blk + m0 + i * 16;
                int g32 = tok >> 5;
                int jo = (tok & 16) >> 2;          // 0 or 4
                ushort4 pk;
                pk.x = f2bf(acc[i][jj][0] + bv);
                pk.y = f2bf(acc[i][jj][1] + bv);
                pk.z = f2bf(acc[i][jj][2] + bv);
                pk.w = f2bf(acc[i][jj][3] + bv);
                *(ushort4*)(Vf + ((size_t)(g32 * NH + hv)) * 2048
                            + (size_t)((td * 4 + quad) * 16 + ct) * 8 + jo) = pk;
            }
        }
    }
}

// ---------------------------------------------------------------------------
// Attention.  (verbatim round-9: block-level LDS staging of K/V, T3-minimum
// schedule, defer-max, deferred-l, cvt_pk pack, setprio.)
// ---------------------------------------------------------------------------
__global__ __launch_bounds__(256) void attn_kernel(
    const u16* __restrict__ Qf, const u16* __restrict__ Kf,
    const u16* __restrict__ Vf, u16* __restrict__ Ob)
{
    __shared__ u16 Ks[2][4096];
    __shared__ u16 Vs[2][4096];

    const int tid = threadIdx.x;
    const int l = tid & 63;
    const int w = tid >> 6;
    const int quad = l >> 4;
    const int c = l & 15;
    const int bid = blockIdx.x;
    const int h = bid & 15;
    const int b = (bid >> 4) & 7;
    const int qt = bid >> 7;
    const int q0 = b * LQ + qt * 64 + w * 16;
    const float C1 = 0.18033688011112042f;   // (1/8)*log2(e)
    const float THR = 8.0f;                  // defer-max threshold

    bf16x8 qf[2];
    {
        size_t qb = ((size_t)((q0 >> 4) * NH + h)) * 1024 + (size_t)l * 8;
        qf[0] = *(const bf16x8*)(Qf + qb);
        qf[1] = *(const bf16x8*)(Qf + qb + 512);
    }

    f32x4 o[4];
    #pragma unroll
    for (int td = 0; td < 4; ++td) o[td] = (f32x4){0.f, 0.f, 0.f, 0.f};
    float m_i = -1e30f;
    float lpart = 0.f;

    auto stage = [&](int buf, int kv0) {
        const int kvg = b * LKV + kv0;
        const int t16 = kvg >> 4;
        const int t32 = kvg >> 5;
        #pragma unroll
        for (int r = 0; r < 2; ++r) {
            const int nt = 2 * r + (w >> 1);
            const u16* ksrc = Kf + ((size_t)((t16 + nt) * NH + h)) * 1024
                            + (w & 1) * 512 + l * 8;
            async16(ksrc, &Ks[buf][r * 2048 + w * 512 + l * 8]);
            const u16* vsrc = Vf + ((size_t)((t32 + r) * NH + h)) * 2048
                            + w * 512 + l * 8;
            async16(vsrc, &Vs[buf][r * 2048 + w * 512 + l * 8]);
        }
    };

    auto step_lds = [&](int buf) {
        f32x4 s[4];
        #pragma unroll
        for (int nt = 0; nt < 4; ++nt) s[nt] = (f32x4){0.f, 0.f, 0.f, 0.f};
        __builtin_amdgcn_s_setprio(1);
        #pragma unroll
        for (int nt = 0; nt < 4; ++nt)
            #pragma unroll
            for (int hk = 0; hk < 2; ++hk) {
                bf16x8 kf = *(const bf16x8*)&Ks[buf][nt * 1024 + hk * 512 + l * 8];
                s[nt] = __builtin_amdgcn_mfma_f32_16x16x32_bf16(
                    kf, qf[hk], s[nt], 0, 0, 0);
            }
        __builtin_amdgcn_s_setprio(0);

        float m01 = fmaxf(fmaxf(s[0][0], s[0][1]), fmaxf(s[0][2], s[0][3]));
        float m23 = fmaxf(fmaxf(s[1][0], s[1][1]), fmaxf(s[1][2], s[1][3]));
        float m45 = fmaxf(fmaxf(s[2][0], s[2][1]), fmaxf(s[2][2], s[2][3]));
        float m67 = fmaxf(fmaxf(s[3][0], s[3][1]), fmaxf(s[3][2], s[3][3]));
        float vml = fmaxf(fmaxf(m01, m23), fmaxf(m45, m67));

        if (!__all(vml - m_i <= THR)) {
            float vmr = vml;
            vmr = fmaxf(vmr, __shfl_xor(vmr, 16, 64));
            vmr = fmaxf(vmr, __shfl_xor(vmr, 32, 64));
            float mnew = fmaxf(m_i, vmr);
            float alpha = __builtin_amdgcn_exp2f((m_i - mnew) * C1);
            m_i = mnew;
            lpart *= alpha;
            float ar_[4];
            #pragma unroll
            for (int r = 0; r < 4; ++r) ar_[r] = __shfl(alpha, quad * 4 + r, 16);
            #pragma unroll
            for (int td = 0; td < 4; ++td)
                #pragma unroll
                for (int r = 0; r < 4; ++r) o[td][r] *= ar_[r];
        }

        float p[4][4];
        float rs = 0.f;
        #pragma unroll
        for (int nt = 0; nt < 4; ++nt)
            #pragma unroll
            for (int r = 0; r < 4; ++r) {
                p[nt][r] = __builtin_amdgcn_exp2f((s[nt][r] - m_i) * C1);
                rs += p[nt][r];
            }
        lpart += rs;

        bf16x8 af[2];
        #pragma unroll
        for (int g = 0; g < 2; ++g) {
            union { unsigned u[4]; bf16x8 v; } r_;
            r_.u[0] = pk2(p[2 * g][0],     p[2 * g][1]);
            r_.u[1] = pk2(p[2 * g][2],     p[2 * g][3]);
            r_.u[2] = pk2(p[2 * g + 1][0], p[2 * g + 1][1]);
            r_.u[3] = pk2(p[2 * g + 1][2], p[2 * g + 1][3]);
            af[g] = r_.v;
        }

        __builtin_amdgcn_s_setprio(1);
        #pragma unroll
        for (int g = 0; g < 2; ++g)
            #pragma unroll
            for (int td = 0; td < 4; ++td) {
                bf16x8 vf = *(const bf16x8*)&Vs[buf][g * 2048 + td * 512 + l * 8];
                o[td] = __builtin_amdgcn_mfma_f32_16x16x32_bf16(
                    af[g], vf, o[td], 0, 0, 0);
            }
        __builtin_amdgcn_s_setprio(0);
    };

    stage(0, 0);
    __syncthreads();
    int cur = 0;
    #pragma unroll 2
    for (int it = 0; it < 16; ++it) {
        if (it < 15) stage(cur ^ 1, (it + 1) * 64);
        step_lds(cur);
        __syncthreads();
        cur ^= 1;
    }

    float l_i = lpart;
    l_i += __shfl_xor(l_i, 16, 64);
    l_i += __shfl_xor(l_i, 32, 64);
    float invl = 1.f / l_i;
    float ir[4];
    #pragma unroll
    for (int r = 0; r < 4; ++r) ir[r] = __shfl(invl, quad * 4 + r, 16);
    #pragma unroll
    for (int td = 0; td < 4; ++td)
        #pragma unroll
        for (int r = 0; r < 4; ++r)
            Ob[(size_t)(q0 + quad * 4 + r) * E_DIM + h * 64 + td * 16 + c] =
                f2bf(o[td][r] * ir[r]);
}

// ---------------------------------------------------------------------------
// Output projection: out[4096,1024] = Ob @ w_out^T + b_out (fp32 out).
// (verbatim round-8/9: 64x64 tiles, grid 1024, swapped operands/float4)
// ---------------------------------------------------------------------------
__global__ __launch_bounds__(256) void out_gemm_kernel(
    const u16* __restrict__ A, const u16* __restrict__ W,
    const float* __restrict__ bias, float* __restrict__ Cf)
{
    __shared__ u16 As[2][64 * 32];
    __shared__ u16 Ws[2][64 * 32];

    const int K = E_DIM, N = E_DIM;
    const int bid = blockIdx.x;
    const int x = bid & 7;
    const int i_ = bid >> 3;            // 0..127
    const int m_blk = (x * 8 + (i_ & 7)) * 64;   // 64 m-blocks
    const int n_blk = (i_ >> 3) * 64;            // 16 n-blocks

    const int tid = threadIdx.x;
    const int l = tid & 63;
    const int w = tid >> 6;
    const int m0 = (w & 1) * 32;
    const int n0 = (w >> 1) * 32;
    const int quad = l >> 4;
    const int c = l & 15;

    f32x4 acc[2][2];
    #pragma unroll
    for (int i = 0; i < 2; ++i)
        #pragma unroll
        for (int j = 0; j < 2; ++j)
            acc[i][j] = (f32x4){0.f, 0.f, 0.f, 0.f};

    const int srow = l >> 2;            // 0..15
    const int skoff = (l & 3) * 8;
    const u16* Ag = A + (size_t)(m_blk + w * 16 + srow) * K + skoff;
    const u16* Wg = W + (size_t)(n_blk + w * 16 + srow) * K + skoff;

    for (int k0 = 0; k0 < K; k0 += 64) {
        __syncthreads();
        #pragma unroll
        for (int hf = 0; hf < 2; ++hf) {
            const size_t soff = (size_t)(k0 + hf * 32);
            const size_t doff = (size_t)(w * 16) * 32;
            async16(Ag + soff, &As[hf][0] + doff);
            async16(Wg + soff, &Ws[hf][0] + doff);
        }
        __syncthreads();

        #pragma unroll
        for (int hf = 0; hf < 2; ++hf) {
            bf16x8 af[2], wf[2];
            #pragma unroll
            for (int t = 0; t < 2; ++t) {
                af[t] = *(const bf16x8*)&As[hf][(m0 + t * 16 + c) * 32 + quad * 8];
                wf[t] = *(const bf16x8*)&Ws[hf][(n0 + t * 16 + c) * 32 + quad * 8];
            }
            #pragma unroll
            for (int i = 0; i < 2; ++i)
                #pragma unroll
                for (int j = 0; j < 2; ++j)
                    acc[i][j] = __builtin_amdgcn_mfma_f32_16x16x32_bf16(
                        wf[j], af[i], acc[i][j], 0, 0, 0);
        }
    }

    #pragma unroll
    for (int j = 0; j < 2; ++j) {
        const int colb = n_blk + n0 + j * 16 + quad * 4;
        const float4 bv = *(const float4*)&bias[colb];
        #pragma unroll
        for (int i = 0; i < 2; ++i) {
            const int row = m_blk + m0 + i * 16 + c;
            float4 o4;
            o4.x = acc[i][j][0] + bv.x;
            o4.y = acc[i][j][1] + bv.y;
            o4.z = acc[i][j][2] + bv.z;
            o4.w = acc[i][j][3] + bv.w;
            *(float4*)&Cf[(size_t)row * N + colb] = o4;
        }
    }
}

// ---------------------------------------------------------------------------
extern "C" void kernel_launch(void* const* d_in, const int* in_sizes, int n_in,
                              void* d_out, int out_size, void* d_ws, size_t ws_size,
                              hipStream_t stream) {
    const float* inputs  = (const float*)d_in[0];   // [8192,1024]
    const float* queries = (const float*)d_in[1];   // [4096,1024]
    const float* w_in    = (const float*)d_in[2];   // [3072,1024]
    const float* b_in    = (const float*)d_in[3];   // [3072]
    const float* w_out   = (const float*)d_in[4];   // [1024,1024]
    const float* b_out   = (const float*)d_in[5];   // [1024]
    float* out = (float*)d_out;                     // [4096,1024] fp32

    const int NQ = BSEG * LQ;    // 4096
    const int NKV = BSEG * LKV;  // 8192

    // workspace: 80 MB
    u16* inputs_b  = (u16*)d_ws;                                   // 16 MB
    u16* queries_b = inputs_b  + (size_t)NKV * E_DIM;              //  8 MB
    u16* w_in_b    = queries_b + (size_t)NQ * E_DIM;               //  6 MB
    u16* w_out_b   = w_in_b    + (size_t)3 * E_DIM * E_DIM;        //  2 MB
    u16* Qf        = w_out_b   + (size_t)E_DIM * E_DIM;            //  8 MB
    u16* Kf        = Qf        + (size_t)NQ * E_DIM;               // 16 MB
    u16* Vf        = Kf        + (size_t)NKV * E_DIM;              // 16 MB
    u16* Ob        = Vf        + (size_t)NKV * E_DIM;              //  8 MB

    dim3 blk(256);

    cvt_all_kernel<<<16384, blk, 0, stream>>>(
        inputs, queries, w_in, w_out, inputs_b, queries_b, w_in_b, w_out_b);

    proj_gemm_kernel<<<1280, blk, 0, stream>>>(
        inputs_b, queries_b, w_in_b, b_in, Kf, Qf, Vf);

    attn_kernel<<<1024, blk, 0, stream>>>(Qf, Kf, Vf, Ob);

    out_gemm_kernel<<<1024, blk, 0, stream>>>(
        Ob, w_out_b, b_out, out);
}